// Round 8
// baseline (440.413 us; speedup 1.0000x reference)
//
#include <hip/hip_runtime.h>
#include <math.h>

// Native clang vector (HIP_vector_type rejected by nontemporal builtins / asm "v").
typedef float fvec4 __attribute__((ext_vector_type(4)));

// ---------------- main kernel: UNCHANGED from R7 (passes, ~59 us) ----------
__device__ __forceinline__ float my_ceil1(float y) {
    float r = rintf(y);
    float d = y - r;
    float e = __expf(-100.0f * d);
    float s = __builtin_amdgcn_rcpf(1.0f + e);
    float f = (r >= 1.0f) ? (r - 1.0f + s)
            : (r <= -1.0f) ? (r + s)
            : 0.0f;
    return fminf(fmaxf(f, -150.0f), 150.0f);
}

__device__ __forceinline__ fvec4 my_ceil4(fvec4 v, fvec4 kc) {
    fvec4 o;
    o.x = my_ceil1(v.x * kc.x);
    o.y = my_ceil1(v.y * kc.y);
    o.z = my_ceil1(v.z * kc.z);
    o.w = my_ceil1(v.w * kc.w);
    return o;
}

__global__ __launch_bounds__(256, 8) void quan_ceil_kernel(
        const fvec4* __restrict__ x4,
        const float* __restrict__ kern,
        fvec4* __restrict__ o4,
        int q) {
    int j = blockIdx.x * blockDim.x + threadIdx.x;
    if (j >= q) return;
    const fvec4* k4 = reinterpret_cast<const fvec4*>(kern);
    int g = j % 3;
    fvec4 kc = (g == 0) ? k4[0] : (g == 1) ? k4[1] : k4[2];
    fvec4 a0 = x4[j];
    fvec4 a1 = x4[j + q];
    fvec4 a2 = x4[j + 2 * q];
    fvec4 a3 = x4[j + 3 * q];
    asm volatile("" : "+v"(a0), "+v"(a1), "+v"(a2), "+v"(a3));
    __builtin_nontemporal_store(my_ceil4(a0, kc), &o4[j]);
    __builtin_nontemporal_store(my_ceil4(a1, kc), &o4[j + q]);
    __builtin_nontemporal_store(my_ceil4(a2, kc), &o4[j + 2 * q]);
    __builtin_nontemporal_store(my_ceil4(a3, kc), &o4[j + 3 * q]);
}

// ---------------- diagnostic A: pure READ bandwidth --------------------------
// Grid-stride, unroll-4 (4 coalesced loads in flight), asm keepalive so loads
// are not DCE'd (rule #17). Reads `passes` x n4w x 16B. No stores.
__global__ __launch_bounds__(256) void diag_read(
        const fvec4* __restrict__ w, int n4w, int passes) {
    int stride = gridDim.x * blockDim.x;
    int j0 = blockIdx.x * blockDim.x + threadIdx.x;
    for (int p = 0; p < passes; ++p) {
        int j = j0;
        for (; j + 3 * stride < n4w; j += 4 * stride) {
            fvec4 v0 = w[j];
            fvec4 v1 = w[j + stride];
            fvec4 v2 = w[j + 2 * stride];
            fvec4 v3 = w[j + 3 * stride];
            asm volatile("" :: "v"(v0), "v"(v1), "v"(v2), "v"(v3));
        }
        for (; j < n4w; j += stride) {
            fvec4 v = w[j];
            asm volatile("" :: "v"(v));
        }
    }
}

// ---------------- diagnostic B: pure COPY (read+write mix) -------------------
// Copies first half of ws -> second half, `passes` times, unroll-4.
__global__ __launch_bounds__(256) void diag_copy(
        const fvec4* __restrict__ src, fvec4* __restrict__ dst,
        int n4h, int passes) {
    int stride = gridDim.x * blockDim.x;
    int j0 = blockIdx.x * blockDim.x + threadIdx.x;
    for (int p = 0; p < passes; ++p) {
        int j = j0;
        for (; j + 3 * stride < n4h; j += 4 * stride) {
            fvec4 v0 = src[j];
            fvec4 v1 = src[j + stride];
            fvec4 v2 = src[j + 2 * stride];
            fvec4 v3 = src[j + 3 * stride];
            asm volatile("" : "+v"(v0), "+v"(v1), "+v"(v2), "+v"(v3));
            dst[j] = v0;
            dst[j + stride] = v1;
            dst[j + 2 * stride] = v2;
            dst[j + 3 * stride] = v3;
        }
        for (; j < n4h; j += stride) {
            dst[j] = src[j];
        }
    }
}

extern "C" void kernel_launch(void* const* d_in, const int* in_sizes, int n_in,
                              void* d_out, int out_size, void* d_ws, size_t ws_size,
                              hipStream_t stream) {
    const float* x = (const float*)d_in[0];
    const float* kern = (const float*)d_in[1];
    float* out = (float*)d_out;

    int n = in_sizes[0];   // 25,165,824
    int n4 = n / 4;        // 6,291,456
    int q = n4 / 4;        // 1,572,864

    const int block = 256;
    int grid = (q + block - 1) / block;   // 6144 blocks

    // 1) correct output (unchanged R7 structure, ~59 us)
    quan_ceil_kernel<<<grid, block, 0, stream>>>(
        reinterpret_cast<const fvec4*>(x), kern,
        reinterpret_cast<fvec4*>(out), q);

    // 2) diagnostics on the ws scratch (0xAA poison = valid tiny floats).
    //    Sized >100 us so they stay inside the top-5 rocprof display window.
    fvec4* w = reinterpret_cast<fvec4*>(d_ws);
    int n4w = (int)(ws_size / 16);        // ~25.1M fvec4 = ~384 MiB
    if (n4w > 0) {
        int n4h = n4w / 2;
        // A: pure-read, 2 x full ws  (~768 MB read)
        diag_read<<<4096, block, 0, stream>>>(w, n4w, 2);
        // B: pure-copy, 2 x half->half (~384 MB read + 384 MB write)
        diag_copy<<<4096, block, 0, stream>>>(w, w + n4h, n4h, 2);
    }
}